// Round 6
// baseline (298.345 us; speedup 1.0000x reference)
//
#include <hip/hip_runtime.h>
#include <hip/hip_cooperative_groups.h>
#include <stdint.h>

namespace cg = cooperative_groups;

#define L_DIM 64
#define R_DIM 2048
#define M_DIM 512      // B*F
#define K_DIM 4096     // 2*R (concat arg1|arg2 along K)
#define N_DIM 2048
#define SPLITK 4
#define KSEG (K_DIM / SPLITK)   // 1024
#define BK 64
#define NSTEP (KSEG / BK)       // 16

typedef _Float16 half_t;
typedef _Float16 half4 __attribute__((ext_vector_type(4)));
typedef _Float16 half8 __attribute__((ext_vector_type(8)));
typedef float f4 __attribute__((ext_vector_type(4)));
typedef float floatx4 __attribute__((ext_vector_type(4)));

__device__ __forceinline__ void gload16(void* lds, const void* g)
{
    __builtin_amdgcn_global_load_lds(
        (const __attribute__((address_space(1))) void*)g,
        (__attribute__((address_space(3))) void*)lds, 16, 0, 0);
}

// One cooperative kernel, 256 blocks x 512 threads (1 block/CU).
// Phase 1: weighted reduce (x -> Ah fp16), cons -> Bh fp16, w-maxes.
// Phase 2: split-K=4 MFMA GEMM [512,4096]x[4096,2048] -> partials.
// Phase 3: partial reduction + root outer product -> out.
__global__ __launch_bounds__(512, 2) void k_all(
    const float* __restrict__ x, const float* __restrict__ w1,
    const float* __restrict__ w2, const float* __restrict__ cl,
    const float* __restrict__ cr, const float* __restrict__ filler,
    const float* __restrict__ role, half_t* __restrict__ Ah,
    half_t* __restrict__ Bh, float* __restrict__ part,
    float* __restrict__ out)
{
    __shared__ char smem[65536];
    const int tid = threadIdx.x;
    const int bid = blockIdx.x;
    cg::grid_group grid = cg::this_grid();

    // ================= phase 1: front =================
    {
        float* w1s = (float*)smem;
        float* w2s = w1s + L_DIM;
        const int b = bid >> 5;                  // rows 2*bid, 2*bid+1 share b
        if (tid < L_DIM) {
            w1s[tid] = w1[b * L_DIM + tid];
            w2s[tid] = w2[b * L_DIM + tid];
        }
        __syncthreads();

        #pragma unroll
        for (int rr = 0; rr < 2; ++rr) {
            const int bf = bid * 2 + rr;
            const int f  = bf & 63;
            const int r0 = tid * 4;              // 512*4 = 2048 = R
            const f4* xp = (const f4*)(x + ((size_t)(b * 4096 + f)) * 2048 + r0);
            float a1x=0.f,a1y=0.f,a1z=0.f,a1w=0.f;
            float a2x=0.f,a2y=0.f,a2z=0.f,a2w=0.f;
            #pragma unroll 8
            for (int l = 0; l < L_DIM; ++l) {
                f4 v = __builtin_nontemporal_load(xp + (size_t)l * (64 * R_DIM / 4));
                float u1 = w1s[l], u2 = w2s[l];
                a1x += v.x*u1; a1y += v.y*u1; a1z += v.z*u1; a1w += v.w*u1;
                a2x += v.x*u2; a2y += v.y*u2; a2z += v.z*u2; a2w += v.w*u2;
            }
            half4 h1 = { (half_t)a1x, (half_t)a1y, (half_t)a1z, (half_t)a1w };
            half4 h2 = { (half_t)a2x, (half_t)a2y, (half_t)a2z, (half_t)a2w };
            *(half4*)(Ah + (size_t)bf * K_DIM + r0) = h1;
            *(half4*)(Ah + (size_t)bf * K_DIM + R_DIM + r0) = h2;
        }

        // cons -> fp16 B^T layout; 1M f4-chunks over 131072 threads = 8 iters
        #pragma unroll
        for (int it = 0; it < 8; ++it) {
            const int i = ((it * 131072) + bid * 512 + tid) * 4;
            const int s = i >> 11;
            const int r = i & 2047;
            f4 vl = __builtin_nontemporal_load((const f4*)(cl + i));
            f4 vr = __builtin_nontemporal_load((const f4*)(cr + i));
            half4 hl = { (half_t)vl.x, (half_t)vl.y, (half_t)vl.z, (half_t)vl.w };
            half4 hr = { (half_t)vr.x, (half_t)vr.y, (half_t)vr.z, (half_t)vr.w };
            *(half4*)(Bh + (size_t)s * K_DIM + r) = hl;
            *(half4*)(Bh + (size_t)s * K_DIM + R_DIM + r) = hr;
        }

        if (bid == 0 && tid < 16) {
            const float* src = (tid < 8) ? w1 : w2;
            const int b8 = tid & 7;
            float m = -1.f;
            #pragma unroll 8
            for (int l = 0; l < L_DIM; ++l)
                m = fmaxf(m, src[b8 * L_DIM + l]);
            out[(size_t)M_DIM * N_DIM + tid] = m;
        }
    }

    __threadfence();
    grid.sync();

    // ================= phase 2: GEMM (split-K=4) =================
    {
        const int lane = tid & 63;
        const int w    = tid >> 6;          // 0..7
        const int wr   = w >> 2;            // 0..1 -> 64 rows each
        const int wc   = w & 3;             // 0..3 -> 32 cols each
        const int z    = bid >> 6;          // 0..3
        const int mblk = (bid >> 4) & 3;
        const int nblk = bid & 15;
        const int m0   = mblk * 128;
        const int n0   = nblk * 128;
        const int kz   = z * KSEG;

        const int srow = lane >> 3;
        const int scol = ((lane & 7) ^ srow) << 3;   // XOR-swizzled source col

        const floatx4 fzero = { 0.f, 0.f, 0.f, 0.f };
        floatx4 acc[4][2];
        #pragma unroll
        for (int i = 0; i < 4; ++i)
            #pragma unroll
            for (int j = 0; j < 2; ++j) acc[i][j] = fzero;

        auto stage = [&](int buf, int kt) {
            half_t* sA = (half_t*)smem + buf * 8192;
            half_t* sB = (half_t*)(smem + 32768) + buf * 8192;
            #pragma unroll
            for (int c = 0; c < 2; ++c) {
                const int rbase = w * 16 + c * 8;    // wave-uniform, mult of 8
                const int row   = rbase + srow;
                gload16(&sA[rbase * 64], Ah + (size_t)(m0 + row) * K_DIM + kt + scol);
                gload16(&sB[rbase * 64], Bh + (size_t)(n0 + row) * K_DIM + kt + scol);
            }
        };

        stage(0, kz);
        __syncthreads();

        const int l15 = lane & 15, l4 = lane >> 4;
        int buf = 0;
        for (int ks = 0; ks < NSTEP; ++ks) {
            if (ks + 1 < NSTEP) stage(buf ^ 1, kz + (ks + 1) * BK);
            half_t* sA = (half_t*)smem + buf * 8192;
            half_t* sB = (half_t*)(smem + 32768) + buf * 8192;
            #pragma unroll
            for (int ksub = 0; ksub < 2; ++ksub) {
                half8 af[4], bf2[2];
                const int cb = ksub * 4 + l4;
                #pragma unroll
                for (int mi = 0; mi < 4; ++mi) {
                    const int row = wr * 64 + mi * 16 + l15;
                    af[mi] = *(const half8*)&sA[row * 64 + ((cb ^ (row & 7)) << 3)];
                }
                #pragma unroll
                for (int ni = 0; ni < 2; ++ni) {
                    const int row = wc * 32 + ni * 16 + l15;
                    bf2[ni] = *(const half8*)&sB[row * 64 + ((cb ^ (row & 7)) << 3)];
                }
                #pragma unroll
                for (int mi = 0; mi < 4; ++mi)
                    #pragma unroll
                    for (int ni = 0; ni < 2; ++ni)
                        acc[mi][ni] = __builtin_amdgcn_mfma_f32_16x16x32_f16(
                            af[mi], bf2[ni], acc[mi][ni], 0, 0, 0);
            }
            __syncthreads();
            buf ^= 1;
        }

        float* P = part + (size_t)z * ((size_t)M_DIM * N_DIM);
        #pragma unroll
        for (int mi = 0; mi < 4; ++mi) {
            const int rb = m0 + wr * 64 + mi * 16 + l4 * 4;
            #pragma unroll
            for (int ni = 0; ni < 2; ++ni) {
                const int cc = n0 + wc * 32 + ni * 16 + l15;
                #pragma unroll
                for (int r = 0; r < 4; ++r)
                    P[(size_t)(rb + r) * N_DIM + cc] = acc[mi][ni][r];
            }
        }
    }

    __threadfence();
    grid.sync();

    // ================= phase 3: split-K reduce + root outer =================
    #pragma unroll
    for (int it = 0; it < 2; ++it) {
        const int idx = ((it * 131072) + bid * 512 + tid) * 4;
        const int mfi = idx >> 11;
        const int s   = idx & 2047;
        f4 a = *(const f4*)(part + idx);
        #pragma unroll
        for (int z = 1; z < SPLITK; ++z) {
            f4 p = *(const f4*)(part + (size_t)z * (M_DIM * (size_t)N_DIM) + idx);
            a.x += p.x; a.y += p.y; a.z += p.z; a.w += p.w;
        }
        const float fl = filler[mfi];
        f4 ro = *(const f4*)(role + s);
        a.x += fl * ro.x; a.y += fl * ro.y; a.z += fl * ro.z; a.w += fl * ro.w;
        *(f4*)(out + idx) = a;
    }
}

extern "C" void kernel_launch(void* const* d_in, const int* in_sizes, int n_in,
                              void* d_out, int out_size, void* d_ws, size_t ws_size,
                              hipStream_t stream)
{
    const float* x      = (const float*)d_in[0];
    const float* w1     = (const float*)d_in[1];
    const float* w2     = (const float*)d_in[2];
    const float* filler = (const float*)d_in[3];
    const float* cl     = (const float*)d_in[4];
    const float* cr     = (const float*)d_in[5];
    const float* role   = (const float*)d_in[6];
    float* out = (float*)d_out;

    char* ws = (char*)d_ws;
    half_t* Ah  = (half_t*)ws;                       // 512*4096*2    = 4 MiB
    half_t* Bh  = (half_t*)(ws + (4u << 20));        // 2048*4096*2   = 16 MiB
    float*  prt = (float*)(ws + (20u << 20));        // 4*512*2048*4  = 16 MiB

    void* args[] = { (void*)&x, (void*)&w1, (void*)&w2, (void*)&cl, (void*)&cr,
                     (void*)&filler, (void*)&role, (void*)&Ah, (void*)&Bh,
                     (void*)&prt, (void*)&out };
    hipLaunchCooperativeKernel((const void*)k_all, dim3(256), dim3(512),
                               args, 0, stream);
}

// Round 7
// 96.551 us; speedup vs baseline: 3.0900x; 3.0900x over previous
//
#include <hip/hip_runtime.h>
#include <stdint.h>

#define L_DIM 64
#define R_DIM 2048
#define M_DIM 512      // B*F
#define K_DIM 4096     // 2*R (concat arg1|arg2 along K)
#define N_DIM 2048

typedef _Float16 half_t;
typedef _Float16 half4 __attribute__((ext_vector_type(4)));
typedef _Float16 half8 __attribute__((ext_vector_type(8)));
typedef float f4 __attribute__((ext_vector_type(4)));
typedef float floatx4 __attribute__((ext_vector_type(4)));

// ---------------- kernel 1: uniform front ----------------
// 512 blocks x 512 threads. Block bf:
//   - weighted reduce of row (b,f) over L -> Ah fp16 (8KB contiguous per l)
//   - 4 chunks of cons_l/cons_r -> fp16 B^T layout
//   - 1 chunk of out-init: out = filler ⊗ role
//   - block 0: w1/w2 row maxes
__global__ __launch_bounds__(512) void k_front(
    const float* __restrict__ x, const float* __restrict__ w1,
    const float* __restrict__ w2, const float* __restrict__ cl,
    const float* __restrict__ cr, const float* __restrict__ filler,
    const float* __restrict__ role, half_t* __restrict__ Ah,
    half_t* __restrict__ Bh, float* __restrict__ out)
{
    const int tid = threadIdx.x;
    const int bf  = blockIdx.x;            // 0..511
    const int b   = bf >> 6;
    const int f   = bf & 63;

    __shared__ float w1s[L_DIM], w2s[L_DIM];
    if (tid < L_DIM) {
        w1s[tid] = w1[b * L_DIM + tid];
        w2s[tid] = w2[b * L_DIM + tid];
    }
    __syncthreads();

    // ---- weighted reduce over L (dominant stream) ----
    {
        const int r0 = tid * 4;                     // 512*4 = 2048 = R
        const f4* xp = (const f4*)(x + ((size_t)(b * 4096 + f)) * 2048 + r0);
        float a1x=0.f,a1y=0.f,a1z=0.f,a1w=0.f;
        float a2x=0.f,a2y=0.f,a2z=0.f,a2w=0.f;
        #pragma unroll 8
        for (int l = 0; l < L_DIM; ++l) {
            f4 v = __builtin_nontemporal_load(xp + (size_t)l * (64 * R_DIM / 4));
            float u1 = w1s[l], u2 = w2s[l];
            a1x += v.x*u1; a1y += v.y*u1; a1z += v.z*u1; a1w += v.w*u1;
            a2x += v.x*u2; a2y += v.y*u2; a2z += v.z*u2; a2w += v.w*u2;
        }
        half4 h1 = { (half_t)a1x, (half_t)a1y, (half_t)a1z, (half_t)a1w };
        half4 h2 = { (half_t)a2x, (half_t)a2y, (half_t)a2z, (half_t)a2w };
        *(half4*)(Ah + (size_t)bf * K_DIM + r0) = h1;
        *(half4*)(Ah + (size_t)bf * K_DIM + R_DIM + r0) = h2;
    }

    // ---- cons -> fp16 B^T layout: 4 contiguous 8KB chunks per block ----
    #pragma unroll
    for (int it = 0; it < 4; ++it) {
        const int i = (((bf * 4 + it) * 512) + tid) * 4;   // 0 .. 4M-4
        const int s = i >> 11;
        const int r = i & 2047;
        f4 vl = __builtin_nontemporal_load((const f4*)(cl + i));
        f4 vr = __builtin_nontemporal_load((const f4*)(cr + i));
        half4 hl = { (half_t)vl.x, (half_t)vl.y, (half_t)vl.z, (half_t)vl.w };
        half4 hr = { (half_t)vr.x, (half_t)vr.y, (half_t)vr.z, (half_t)vr.w };
        *(half4*)(Bh + (size_t)s * K_DIM + r) = hl;
        *(half4*)(Bh + (size_t)s * K_DIM + R_DIM + r) = hr;
    }

    // ---- out init: out = filler ⊗ role (GEMM atomically accumulates) ----
    {
        const int j   = (bf * 512 + tid) * 4;       // 0 .. 1M-4
        const int mfi = j >> 11;
        const int s   = j & 2047;
        const float fl = filler[mfi];
        f4 ro = *(const f4*)(role + s);
        f4 o = { fl * ro.x, fl * ro.y, fl * ro.z, fl * ro.w };
        *(f4*)(out + j) = o;
    }

    // ---- w maxes ----
    if (bf == 0 && tid < 16) {
        const float* src = (tid < 8) ? w1 : w2;
        const int b8 = tid & 7;
        float m = -1.f;
        #pragma unroll 8
        for (int l = 0; l < L_DIM; ++l)
            m = fmaxf(m, src[b8 * L_DIM + l]);
        out[(size_t)M_DIM * N_DIM + tid] = m;
    }
}

// ---------------- kernel 2: MFMA GEMM, split-K=8, atomic epilogue ----------------
__device__ __forceinline__ void gload16(void* lds, const void* g)
{
    __builtin_amdgcn_global_load_lds(
        (const __attribute__((address_space(1))) void*)g,
        (__attribute__((address_space(3))) void*)lds, 16, 0, 0);
}

#define BM 128
#define BN 128
#define BK 64
#define SPLITK 8
#define KSEG (K_DIM / SPLITK)  // 512
#define NSTEP (KSEG / BK)      // 8

__global__ __launch_bounds__(256) void k_gemm(
    const half_t* __restrict__ Ah, const half_t* __restrict__ Bh,
    float* __restrict__ out)
{
    __shared__ half_t sA[2][BM * BK];
    __shared__ half_t sB[2][BN * BK];
    const int tid  = threadIdx.x;
    const int lane = tid & 63;
    const int w    = tid >> 6;           // wave 0..3
    const int wr   = w >> 1, wc = w & 1; // 2x2 wave grid, 64x64 each
    const int m0   = blockIdx.y * BM;
    const int n0   = blockIdx.x * BN;
    const int kz   = blockIdx.z * KSEG;

    const int srow = lane >> 3;                    // dest row within 8-row chunk
    const int scol = ((lane & 7) ^ srow) << 3;     // swizzled source col (halfs)

    const floatx4 fzero = { 0.f, 0.f, 0.f, 0.f };
    floatx4 acc[4][4];
    #pragma unroll
    for (int i = 0; i < 4; ++i)
        #pragma unroll
        for (int j = 0; j < 4; ++j) acc[i][j] = fzero;

    auto stage = [&](int buf, int kt) {
        #pragma unroll
        for (int c = 0; c < 4; ++c) {
            const int rbase = w * 32 + c * 8;      // wave-uniform
            const int row   = rbase + srow;
            gload16(&sA[buf][rbase * BK], Ah + (size_t)(m0 + row) * K_DIM + kt + scol);
            gload16(&sB[buf][rbase * BK], Bh + (size_t)(n0 + row) * K_DIM + kt + scol);
        }
    };

    stage(0, kz);
    __syncthreads();

    const int l15 = lane & 15, l4 = lane >> 4;
    int buf = 0;
    for (int ks = 0; ks < NSTEP; ++ks) {
        if (ks + 1 < NSTEP) stage(buf ^ 1, kz + (ks + 1) * BK);
        #pragma unroll
        for (int ksub = 0; ksub < 2; ++ksub) {
            half8 af[4], bfr[4];
            const int cb = ksub * 4 + l4;          // logical col-block 0..7
            #pragma unroll
            for (int mi = 0; mi < 4; ++mi) {
                const int row = wr * 64 + mi * 16 + l15;
                af[mi] = *(const half8*)&sA[buf][row * BK + ((cb ^ (row & 7)) << 3)];
            }
            #pragma unroll
            for (int ni = 0; ni < 4; ++ni) {
                const int row = wc * 64 + ni * 16 + l15;
                bfr[ni] = *(const half8*)&sB[buf][row * BK + ((cb ^ (row & 7)) << 3)];
            }
            #pragma unroll
            for (int mi = 0; mi < 4; ++mi)
                #pragma unroll
                for (int ni = 0; ni < 4; ++ni)
                    acc[mi][ni] = __builtin_amdgcn_mfma_f32_16x16x32_f16(
                        af[mi], bfr[ni], acc[mi][ni], 0, 0, 0);
        }
        __syncthreads();
        buf ^= 1;
    }

    // atomic accumulate into pre-initialized out (root ⊗ role already there)
    #pragma unroll
    for (int mi = 0; mi < 4; ++mi) {
        const int rb = m0 + wr * 64 + mi * 16 + l4 * 4;
        #pragma unroll
        for (int ni = 0; ni < 4; ++ni) {
            const int cc = n0 + wc * 64 + ni * 16 + l15;
            #pragma unroll
            for (int r = 0; r < 4; ++r)
                atomicAdd(&out[(size_t)(rb + r) * N_DIM + cc], acc[mi][ni][r]);
        }
    }
}

extern "C" void kernel_launch(void* const* d_in, const int* in_sizes, int n_in,
                              void* d_out, int out_size, void* d_ws, size_t ws_size,
                              hipStream_t stream)
{
    const float* x      = (const float*)d_in[0];
    const float* w1     = (const float*)d_in[1];
    const float* w2     = (const float*)d_in[2];
    const float* filler = (const float*)d_in[3];
    const float* cl     = (const float*)d_in[4];
    const float* cr     = (const float*)d_in[5];
    const float* role   = (const float*)d_in[6];
    float* out = (float*)d_out;

    char* ws = (char*)d_ws;
    half_t* Ah  = (half_t*)ws;                       // 512*4096*2   = 4 MiB
    half_t* Bh  = (half_t*)(ws + (4u << 20));        // 2048*4096*2  = 16 MiB

    hipLaunchKernelGGL(k_front, dim3(512), dim3(512), 0, stream,
                       x, w1, w2, cl, cr, filler, role, Ah, Bh, out);
    hipLaunchKernelGGL(k_gemm,  dim3(N_DIM / BN, M_DIM / BM, SPLITK), dim3(256), 0, stream,
                       Ah, Bh, out);
}